// Round 4
// baseline (856.832 us; speedup 1.0000x reference)
//
#include <hip/hip_runtime.h>
#include <math.h>

#define BB      32
#define H_KVN   8
#define GQ      4
#define H_QN    32
#define DD      128
#define PAGEN   16
#define PAGESN  128
#define NSPLITS 16

// (1/sqrt(128)) * log2(e): softmax in exp2 domain -> single v_exp_f32
#define SCALE2  (0.08838834764831845f * 1.4426950408889634f)
#define NEG_INF (-__builtin_huge_valf())

// Sum across each 16-lane DPP row via row_ror butterfly (8,4,2,1).
// VALU-only: no DS traffic, ~4cy/step vs ~30cy for ds_swizzle-based __shfl_xor.
// Requires all 16 lanes of the row active (guards in this kernel are row-uniform).
__device__ __forceinline__ float row_reduce_add(float v) {
    int x;
    x = __builtin_amdgcn_update_dpp(0, __float_as_int(v), 0x128, 0xf, 0xf, true); v += __int_as_float(x); // ror:8
    x = __builtin_amdgcn_update_dpp(0, __float_as_int(v), 0x124, 0xf, 0xf, true); v += __int_as_float(x); // ror:4
    x = __builtin_amdgcn_update_dpp(0, __float_as_int(v), 0x122, 0xf, 0xf, true); v += __int_as_float(x); // ror:2
    x = __builtin_amdgcn_update_dpp(0, __float_as_int(v), 0x121, 0xf, 0xf, true); v += __int_as_float(x); // ror:1
    return v;
}

__device__ __forceinline__ float dot8(const float4& a0, const float4& a1,
                                      const float4& b0, const float4& b1) {
    return a0.x*b0.x + a0.y*b0.y + a0.z*b0.z + a0.w*b0.w
         + a1.x*b1.x + a1.y*b1.y + a1.z*b1.z + a1.w*b1.w;
}

// Fused split-K decode attention. grid = B*H_KV*NSPLITS, block = 256 (4 waves).
// Each 16-lane row owns one position, lane l16 owns d = l16*8..+8. Unroll 2
// positions per row per iteration (8 loads in flight). The last block per (b,h)
// (device-scope atomic ticket) merges all split partials and writes out.
__global__ __launch_bounds__(256)
void paged_decode_fused(const float* __restrict__ q,
                        const float* __restrict__ knew,
                        const float* __restrict__ vnew,
                        const float* __restrict__ kcache,
                        const float* __restrict__ vcache,
                        const int*   __restrict__ btab,
                        const int*   __restrict__ ctx_lens,
                        int*         __restrict__ cnt,
                        float*       __restrict__ ws_o,
                        float*       __restrict__ ws_ml,
                        float*       __restrict__ out)
{
    const int bid = blockIdx.x;
    const int s   = bid % NSPLITS;
    const int bh  = bid / NSPLITS;       // b*H_KV + h
    const int h   = bh % H_KVN;
    const int b   = bh / H_KVN;
    const int tid  = threadIdx.x;
    const int w    = tid >> 6;           // wave 0..3
    const int lane = tid & 63;
    const int g16  = lane >> 4;          // row (position sub-index) 0..3
    const int l16  = lane & 15;          // d-slice owner

    const int ctx   = ctx_lens[b];
    const int chunk = (((ctx + NSPLITS - 1) / NSPLITS) + 15) & ~15;  // page-aligned
    const int start = s * chunk;
    const int end   = min(start + chunk, ctx);
    const int cend  = min(end, ctx - 1);   // cache-resident portion of this split

    // q fragments: 4 grouped heads x 8 floats at d = l16*8
    float4 qa[GQ], qb[GQ];
    {
        const float* qp = q + ((size_t)b * H_QN + (size_t)h * GQ) * DD + l16 * 8;
        #pragma unroll
        for (int g = 0; g < GQ; ++g) {
            qa[g] = *(const float4*)(qp + g * DD);
            qb[g] = *(const float4*)(qp + g * DD + 4);
        }
    }

    float m[GQ], l[GQ], o[GQ][8];
    #pragma unroll
    for (int g = 0; g < GQ; ++g) {
        m[g] = NEG_INF; l[g] = 0.f;
        #pragma unroll
        for (int j = 0; j < 8; ++j) o[g][j] = 0.f;
    }

    const int* btb = btab + b * PAGESN;

    // Prologue: the new token (position ctx-1) lives in k/v, NOT the cache
    // (we must never write the input caches). Handled once, by wave 0 row 0 of
    // the owning split, while the softmax state is still empty: m=sc, l=1, o=v.
    if (w == 0 && g16 == 0 && start <= ctx - 1 && ctx - 1 < end) {
        const size_t off = ((size_t)b * H_KVN + h) * DD + l16 * 8;
        const float4 ka = *(const float4*)(knew + off);
        const float4 kb = *(const float4*)(knew + off + 4);
        const float4 va = *(const float4*)(vnew + off);
        const float4 vb = *(const float4*)(vnew + off + 4);
        const float ve[8] = { va.x, va.y, va.z, va.w, vb.x, vb.y, vb.z, vb.w };
        #pragma unroll
        for (int g = 0; g < GQ; ++g) {
            float d0 = row_reduce_add(dot8(qa[g], qb[g], ka, kb));
            m[g] = d0 * SCALE2;
            l[g] = 1.f;
            #pragma unroll
            for (int j = 0; j < 8; ++j) o[g][j] = ve[j];
        }
    }

    // Main loop: branch-free over cache-resident positions, 2 positions per row
    // per iteration (block-iter = 32 consecutive positions = 2 pages).
    for (int p0 = start + w * 8; p0 < cend; p0 += 32) {
        const int pA = p0 + g16;
        if (pA < cend) {
            const int  pB  = pA + 4;
            const bool okB = (pB < cend);
            const int slotA = btb[pA >> 4] * PAGEN + (pA & (PAGEN - 1));
            const size_t offA = ((size_t)slotA * H_KVN + h) * DD + l16 * 8;
            const float4 kA0 = *(const float4*)(kcache + offA);
            const float4 kA1 = *(const float4*)(kcache + offA + 4);
            const float4 vA0 = *(const float4*)(vcache + offA);
            const float4 vA1 = *(const float4*)(vcache + offA + 4);
            float4 kB0 = {0,0,0,0}, kB1 = {0,0,0,0}, vB0 = {0,0,0,0}, vB1 = {0,0,0,0};
            if (okB) {
                const int slotB = btb[pB >> 4] * PAGEN + (pB & (PAGEN - 1));
                const size_t offB = ((size_t)slotB * H_KVN + h) * DD + l16 * 8;
                kB0 = *(const float4*)(kcache + offB);
                kB1 = *(const float4*)(kcache + offB + 4);
                vB0 = *(const float4*)(vcache + offB);
                vB1 = *(const float4*)(vcache + offB + 4);
            }
            float dA[GQ], dB[GQ];
            #pragma unroll
            for (int g = 0; g < GQ; ++g) {
                dA[g] = dot8(qa[g], qb[g], kA0, kA1);
                dB[g] = dot8(qa[g], qb[g], kB0, kB1);
            }
            #pragma unroll
            for (int g = 0; g < GQ; ++g) {
                dA[g] = row_reduce_add(dA[g]);
                dB[g] = row_reduce_add(dB[g]);
            }
            const float vAe[8] = { vA0.x, vA0.y, vA0.z, vA0.w, vA1.x, vA1.y, vA1.z, vA1.w };
            const float vBe[8] = { vB0.x, vB0.y, vB0.z, vB0.w, vB1.x, vB1.y, vB1.z, vB1.w };
            #pragma unroll
            for (int g = 0; g < GQ; ++g) {
                const float scA  = dA[g] * SCALE2;
                const float scB  = okB ? dB[g] * SCALE2 : NEG_INF;
                const float nm   = fmaxf(m[g], fmaxf(scA, scB));
                const float corr = exp2f(m[g] - nm);   // m=-inf -> 0; nm always finite here
                const float pa   = exp2f(scA - nm);
                const float pb   = exp2f(scB - nm);    // scB=-inf -> 0
                l[g] = l[g] * corr + pa + pb;
                m[g] = nm;
                #pragma unroll
                for (int j = 0; j < 8; ++j)
                    o[g][j] = o[g][j] * corr + pa * vAe[j] + pb * vBe[j];
            }
        }
    }

    // Merge the 4 rows of this wave (lane^16, lane^32); d-layout identical per row.
    #pragma unroll
    for (int msk = 16; msk <= 32; msk <<= 1) {
        #pragma unroll
        for (int g = 0; g < GQ; ++g) {
            const float mo = __shfl_xor(m[g], msk);
            const float lo = __shfl_xor(l[g], msk);
            const float M  = fmaxf(m[g], mo);
            const float c1 = (m[g] == NEG_INF) ? 0.f : exp2f(m[g] - M);
            const float c2 = (mo   == NEG_INF) ? 0.f : exp2f(mo   - M);
            l[g] = l[g] * c1 + lo * c2;
            #pragma unroll
            for (int j = 0; j < 8; ++j) {
                const float oo = __shfl_xor(o[g][j], msk);
                o[g][j] = o[g][j] * c1 + oo * c2;
            }
            m[g] = M;
        }
    }

    // Merge the 4 waves via LDS -> block partial -> workspace.
    __shared__ float o_lds[4][GQ][DD];       // 8 KB
    __shared__ float m_lds[4][GQ];
    __shared__ float l_lds[4][GQ];
    if (g16 == 0) {
        #pragma unroll
        for (int g = 0; g < GQ; ++g)
            #pragma unroll
            for (int j = 0; j < 8; ++j)
                o_lds[w][g][l16 * 8 + j] = o[g][j];
    }
    if (lane == 0) {
        #pragma unroll
        for (int g = 0; g < GQ; ++g) { m_lds[w][g] = m[g]; l_lds[w][g] = l[g]; }
    }
    __syncthreads();

    const size_t idx = (size_t)bh * NSPLITS + s;
    float* op  = ws_o  + idx * (GQ * DD);
    float* mlp = ws_ml + idx * (GQ * 2);

    for (int e = tid; e < GQ * DD; e += 256) {
        const int g = e >> 7;
        const int d = e & (DD - 1);
        const float M = fmaxf(fmaxf(m_lds[0][g], m_lds[1][g]),
                              fmaxf(m_lds[2][g], m_lds[3][g]));
        float acc = 0.f;
        #pragma unroll
        for (int ww = 0; ww < 4; ++ww) {
            const float mw  = m_lds[ww][g];
            const float wgt = (mw == NEG_INF) ? 0.f : exp2f(mw - M);
            acc += o_lds[ww][g][d] * wgt;
        }
        op[e] = acc;
    }
    if (tid < GQ) {
        const int g = tid;
        const float M = fmaxf(fmaxf(m_lds[0][g], m_lds[1][g]),
                              fmaxf(m_lds[2][g], m_lds[3][g]));
        float L = 0.f;
        #pragma unroll
        for (int ww = 0; ww < 4; ++ww) {
            const float mw  = m_lds[ww][g];
            const float wgt = (mw == NEG_INF) ? 0.f : exp2f(mw - M);
            L += l_lds[ww][g] * wgt;
        }
        mlp[g * 2]     = M;
        mlp[g * 2 + 1] = L;
    }

    // Last finishing block for this (b,h) merges all splits (release/acquire via
    // device-scope fences around a device-scope atomic ticket).
    __threadfence();                        // release our partial to device scope
    __shared__ int ticket;
    if (tid == 0) ticket = atomicAdd(&cnt[bh], 1);
    __syncthreads();
    if (ticket != NSPLITS - 1) return;
    __threadfence();                        // acquire other blocks' partials

    const float* mlp_all = ws_ml + (size_t)bh * NSPLITS * (GQ * 2);
    __shared__ float ML[GQ][2];
    if (tid < GQ) {
        const int g = tid;
        float M = NEG_INF;
        for (int s2 = 0; s2 < NSPLITS; ++s2)
            M = fmaxf(M, mlp_all[s2 * GQ * 2 + g * 2]);
        float L = 0.f;
        for (int s2 = 0; s2 < NSPLITS; ++s2) {
            const float mw  = mlp_all[s2 * GQ * 2 + g * 2];
            const float wgt = (mw == NEG_INF) ? 0.f : exp2f(mw - M);
            L += mlp_all[s2 * GQ * 2 + g * 2 + 1] * wgt;
        }
        ML[g][0] = M;
        ML[g][1] = L;   // ctx >= 1 guarantees L > 0
    }
    __syncthreads();

    const float* op_all = ws_o + (size_t)bh * NSPLITS * (GQ * DD);
    float* outp = out + ((size_t)b * H_QN + (size_t)h * GQ) * DD;
    for (int e = tid; e < GQ * DD; e += 256) {
        const int g = e >> 7;
        const float M = ML[g][0], L = ML[g][1];
        float acc = 0.f;
        for (int s2 = 0; s2 < NSPLITS; ++s2) {
            const float mw  = mlp_all[s2 * GQ * 2 + g * 2];
            const float wgt = (mw == NEG_INF) ? 0.f : exp2f(mw - M);
            acc += op_all[s2 * GQ * DD + e] * wgt;
        }
        outp[e] = acc / L;
    }
}

extern "C" void kernel_launch(void* const* d_in, const int* in_sizes, int n_in,
                              void* d_out, int out_size, void* d_ws, size_t ws_size,
                              hipStream_t stream) {
    const float* q  = (const float*)d_in[0];
    const float* k  = (const float*)d_in[1];
    const float* v  = (const float*)d_in[2];
    const float* kc = (const float*)d_in[3];
    const float* vc = (const float*)d_in[4];
    // d_in[5] slot_mapping: unused — derived from block_tables + context_lens
    const int* bt   = (const int*)d_in[6];
    const int* ctx  = (const int*)d_in[7];
    float* out = (float*)d_out;

    // ws layout: [256 ints: tickets][ws_o: 256*NSPLITS*512 f][ws_ml: 256*NSPLITS*8 f]
    int*   cnt   = (int*)d_ws;
    float* ws_o  = (float*)d_ws + 256;                       // 1 KB offset
    float* ws_ml = ws_o + (size_t)BB * H_KVN * NSPLITS * (GQ * DD);

    hipMemsetAsync(cnt, 0, BB * H_KVN * sizeof(int), stream);  // reset tickets each call

    paged_decode_fused<<<BB * H_KVN * NSPLITS, 256, 0, stream>>>(
        q, k, v, kc, vc, bt, ctx, cnt, ws_o, ws_ml, out);
}

// Round 5
// 66.671 us; speedup vs baseline: 12.8517x; 12.8517x over previous
//
#include <hip/hip_runtime.h>
#include <math.h>

#define BB      32
#define H_KVN   8
#define GQ      4
#define H_QN    32
#define DD      128
#define PAGEN   16
#define PAGESN  128
#define NSPLIT_MAX 16

// (1/sqrt(128)) * log2(e): softmax in exp2 domain -> single v_exp_f32
#define SCALE2  (0.08838834764831845f * 1.4426950408889634f)
#define NEG_INF (-__builtin_huge_valf())

// Sum across each 16-lane DPP row via row_ror butterfly (8,4,2,1).
// VALU-only: no DS traffic, no lgkmcnt waits. Verified correct in R4 (absmax 4.9e-4).
__device__ __forceinline__ float row_reduce_add(float v) {
    int x;
    x = __builtin_amdgcn_update_dpp(0, __float_as_int(v), 0x128, 0xf, 0xf, true); v += __int_as_float(x); // row_ror:8
    x = __builtin_amdgcn_update_dpp(0, __float_as_int(v), 0x124, 0xf, 0xf, true); v += __int_as_float(x); // row_ror:4
    x = __builtin_amdgcn_update_dpp(0, __float_as_int(v), 0x122, 0xf, 0xf, true); v += __int_as_float(x); // row_ror:2
    x = __builtin_amdgcn_update_dpp(0, __float_as_int(v), 0x121, 0xf, 0xf, true); v += __int_as_float(x); // row_ror:1
    return v;
}

__device__ __forceinline__ float dot8(const float4& a0, const float4& a1,
                                      const float4& b0, const float4& b1) {
    return a0.x*b0.x + a0.y*b0.y + a0.z*b0.z + a0.w*b0.w
         + a1.x*b1.x + a1.y*b1.y + a1.z*b1.z + a1.w*b1.w;
}

// Kernel 1: split-K partial attention. grid = B*H_KV*nsplits, block = 256 (4 waves).
// Each 16-lane row owns one position; lane l16 owns d = l16*8..+8. Two positions per
// row per iteration (8 dwordx4 loads in flight). NO device-scope fences/atomics —
// merge happens in a second tiny kernel (R4 showed per-block __threadfence = L2
// flush per block = 10x regression on CDNA4).
__global__ __launch_bounds__(256)
void paged_decode_partial(const float* __restrict__ q,
                          const float* __restrict__ knew,
                          const float* __restrict__ vnew,
                          const float* __restrict__ kcache,
                          const float* __restrict__ vcache,
                          const int*   __restrict__ btab,
                          const int*   __restrict__ ctx_lens,
                          float*       __restrict__ ws_o,
                          float*       __restrict__ ws_ml,
                          int nsplits)
{
    const int bid = blockIdx.x;
    const int s   = bid % nsplits;
    const int bh  = bid / nsplits;       // b*H_KV + h
    const int h   = bh % H_KVN;
    const int b   = bh / H_KVN;
    const int tid  = threadIdx.x;
    const int w    = tid >> 6;           // wave 0..3
    const int lane = tid & 63;
    const int g16  = lane >> 4;          // row (position sub-index) 0..3
    const int l16  = lane & 15;          // d-slice owner

    const int ctx   = ctx_lens[b];
    const int chunk = (((ctx + nsplits - 1) / nsplits) + 15) & ~15;  // page-aligned
    const int start = s * chunk;
    const int end   = min(start + chunk, ctx);
    const int cend  = min(end, ctx - 1);   // cache-resident portion of this split

    // q fragments: 4 grouped heads x 8 floats at d = l16*8
    float4 qa[GQ], qb[GQ];
    {
        const float* qp = q + ((size_t)b * H_QN + (size_t)h * GQ) * DD + l16 * 8;
        #pragma unroll
        for (int g = 0; g < GQ; ++g) {
            qa[g] = *(const float4*)(qp + g * DD);
            qb[g] = *(const float4*)(qp + g * DD + 4);
        }
    }

    float m[GQ], l[GQ], o[GQ][8];
    #pragma unroll
    for (int g = 0; g < GQ; ++g) {
        m[g] = NEG_INF; l[g] = 0.f;
        #pragma unroll
        for (int j = 0; j < 8; ++j) o[g][j] = 0.f;
    }

    const int* btb = btab + b * PAGESN;

    // Prologue: new token (position ctx-1) is read from k/v, never from (or
    // written to) the cache inputs. Done once by wave 0 row 0 of the owning
    // split while state is empty: m=sc, l=1, o=v.
    if (w == 0 && g16 == 0 && start <= ctx - 1 && ctx - 1 < end) {
        const size_t off = ((size_t)b * H_KVN + h) * DD + l16 * 8;
        const float4 ka = *(const float4*)(knew + off);
        const float4 kb = *(const float4*)(knew + off + 4);
        const float4 va = *(const float4*)(vnew + off);
        const float4 vb = *(const float4*)(vnew + off + 4);
        const float ve[8] = { va.x, va.y, va.z, va.w, vb.x, vb.y, vb.z, vb.w };
        #pragma unroll
        for (int g = 0; g < GQ; ++g) {
            float d0 = row_reduce_add(dot8(qa[g], qb[g], ka, kb));
            m[g] = d0 * SCALE2;
            l[g] = 1.f;
            #pragma unroll
            for (int j = 0; j < 8; ++j) o[g][j] = ve[j];
        }
    }

    // Main loop: branch-free over cache-resident positions, 2 positions per row
    // per iteration (block-iteration = 32 consecutive positions = 2 pages).
    for (int p0 = start + w * 8; p0 < cend; p0 += 32) {
        const int pA = p0 + g16;
        if (pA < cend) {
            const int  pB  = pA + 4;
            const bool okB = (pB < cend);
            const int slotA = btb[pA >> 4] * PAGEN + (pA & (PAGEN - 1));
            const size_t offA = ((size_t)slotA * H_KVN + h) * DD + l16 * 8;
            const float4 kA0 = *(const float4*)(kcache + offA);
            const float4 kA1 = *(const float4*)(kcache + offA + 4);
            const float4 vA0 = *(const float4*)(vcache + offA);
            const float4 vA1 = *(const float4*)(vcache + offA + 4);
            float4 kB0 = {0,0,0,0}, kB1 = {0,0,0,0}, vB0 = {0,0,0,0}, vB1 = {0,0,0,0};
            if (okB) {
                const int slotB = btb[pB >> 4] * PAGEN + (pB & (PAGEN - 1));
                const size_t offB = ((size_t)slotB * H_KVN + h) * DD + l16 * 8;
                kB0 = *(const float4*)(kcache + offB);
                kB1 = *(const float4*)(kcache + offB + 4);
                vB0 = *(const float4*)(vcache + offB);
                vB1 = *(const float4*)(vcache + offB + 4);
            }
            float dA[GQ], dB[GQ];
            #pragma unroll
            for (int g = 0; g < GQ; ++g) {
                dA[g] = dot8(qa[g], qb[g], kA0, kA1);
                dB[g] = dot8(qa[g], qb[g], kB0, kB1);
            }
            #pragma unroll
            for (int g = 0; g < GQ; ++g) {
                dA[g] = row_reduce_add(dA[g]);
                dB[g] = row_reduce_add(dB[g]);
            }
            const float vAe[8] = { vA0.x, vA0.y, vA0.z, vA0.w, vA1.x, vA1.y, vA1.z, vA1.w };
            const float vBe[8] = { vB0.x, vB0.y, vB0.z, vB0.w, vB1.x, vB1.y, vB1.z, vB1.w };
            #pragma unroll
            for (int g = 0; g < GQ; ++g) {
                const float scA  = dA[g] * SCALE2;
                const float scB  = okB ? dB[g] * SCALE2 : NEG_INF;
                const float nm   = fmaxf(m[g], fmaxf(scA, scB));
                const float corr = exp2f(m[g] - nm);   // m=-inf -> 0; nm finite here
                const float pa   = exp2f(scA - nm);
                const float pb   = exp2f(scB - nm);    // scB=-inf -> 0
                l[g] = l[g] * corr + pa + pb;
                m[g] = nm;
                #pragma unroll
                for (int j = 0; j < 8; ++j)
                    o[g][j] = o[g][j] * corr + pa * vAe[j] + pb * vBe[j];
            }
        }
    }

    // Merge the 4 rows of this wave (lane^16, lane^32); d-layout identical per row.
    #pragma unroll
    for (int msk = 16; msk <= 32; msk <<= 1) {
        #pragma unroll
        for (int g = 0; g < GQ; ++g) {
            const float mo = __shfl_xor(m[g], msk);
            const float lo = __shfl_xor(l[g], msk);
            const float M  = fmaxf(m[g], mo);
            const float c1 = (m[g] == NEG_INF) ? 0.f : exp2f(m[g] - M);
            const float c2 = (mo   == NEG_INF) ? 0.f : exp2f(mo   - M);
            l[g] = l[g] * c1 + lo * c2;
            #pragma unroll
            for (int j = 0; j < 8; ++j) {
                const float oo = __shfl_xor(o[g][j], msk);
                o[g][j] = o[g][j] * c1 + oo * c2;
            }
            m[g] = M;
        }
    }

    // Merge the 4 waves via LDS -> block partial -> workspace.
    __shared__ float o_lds[4][GQ][DD];       // 8 KB
    __shared__ float m_lds[4][GQ];
    __shared__ float l_lds[4][GQ];
    if (g16 == 0) {
        #pragma unroll
        for (int g = 0; g < GQ; ++g)
            #pragma unroll
            for (int j = 0; j < 8; ++j)
                o_lds[w][g][l16 * 8 + j] = o[g][j];
    }
    if (lane == 0) {
        #pragma unroll
        for (int g = 0; g < GQ; ++g) { m_lds[w][g] = m[g]; l_lds[w][g] = l[g]; }
    }
    __syncthreads();

    const size_t idx = (size_t)bh * nsplits + s;
    float* op  = ws_o  + idx * (GQ * DD);
    float* mlp = ws_ml + idx * (GQ * 2);

    for (int e = tid; e < GQ * DD; e += 256) {
        const int g = e >> 7;
        const int d = e & (DD - 1);
        const float M = fmaxf(fmaxf(m_lds[0][g], m_lds[1][g]),
                              fmaxf(m_lds[2][g], m_lds[3][g]));
        float acc = 0.f;
        #pragma unroll
        for (int ww = 0; ww < 4; ++ww) {
            const float mw  = m_lds[ww][g];
            const float wgt = (mw == NEG_INF) ? 0.f : exp2f(mw - M);
            acc += o_lds[ww][g][d] * wgt;
        }
        op[e] = acc;
    }
    if (tid < GQ) {
        const int g = tid;
        const float M = fmaxf(fmaxf(m_lds[0][g], m_lds[1][g]),
                              fmaxf(m_lds[2][g], m_lds[3][g]));
        float L = 0.f;
        #pragma unroll
        for (int ww = 0; ww < 4; ++ww) {
            const float mw  = m_lds[ww][g];
            const float wgt = (mw == NEG_INF) ? 0.f : exp2f(mw - M);
            L += l_lds[ww][g] * wgt;
        }
        mlp[g * 2]     = M;
        mlp[g * 2 + 1] = L;
    }
}

// Kernel 2: combine split partials and normalize. grid = B*H_KV, block = 256.
__global__ __launch_bounds__(256)
void paged_decode_reduce(const float* __restrict__ ws_o,
                         const float* __restrict__ ws_ml,
                         float*       __restrict__ out,
                         int nsplits)
{
    const int bh  = blockIdx.x;            // b*H_KV + h
    const int tid = threadIdx.x;
    __shared__ float ML[GQ][2];

    const float* mlp = ws_ml + (size_t)bh * nsplits * (GQ * 2);
    if (tid < GQ) {
        const int g = tid;
        float M = NEG_INF;
        for (int s = 0; s < nsplits; ++s)
            M = fmaxf(M, mlp[s * GQ * 2 + g * 2]);
        float L = 0.f;
        for (int s = 0; s < nsplits; ++s) {
            const float mw  = mlp[s * GQ * 2 + g * 2];
            const float wgt = (mw == NEG_INF) ? 0.f : exp2f(mw - M);
            L += mlp[s * GQ * 2 + g * 2 + 1] * wgt;
        }
        ML[g][0] = M;
        ML[g][1] = L;   // ctx >= 1 guarantees L > 0
    }
    __syncthreads();

    const float* op = ws_o + (size_t)bh * nsplits * (GQ * DD);
    const int b = bh / H_KVN, h = bh % H_KVN;
    float* outp = out + ((size_t)b * H_QN + (size_t)h * GQ) * DD;

    for (int e = tid; e < GQ * DD; e += 256) {
        const int g = e >> 7;
        const float M = ML[g][0], L = ML[g][1];
        float acc = 0.f;
        for (int s = 0; s < nsplits; ++s) {
            const float mw  = mlp[s * GQ * 2 + g * 2];
            const float wgt = (mw == NEG_INF) ? 0.f : exp2f(mw - M);
            acc += op[s * GQ * DD + e] * wgt;
        }
        outp[e] = acc / L;
    }
}

extern "C" void kernel_launch(void* const* d_in, const int* in_sizes, int n_in,
                              void* d_out, int out_size, void* d_ws, size_t ws_size,
                              hipStream_t stream) {
    const float* q  = (const float*)d_in[0];
    const float* k  = (const float*)d_in[1];
    const float* v  = (const float*)d_in[2];
    const float* kc = (const float*)d_in[3];
    const float* vc = (const float*)d_in[4];
    // d_in[5] slot_mapping: unused — derived from block_tables + context_lens
    const int* bt   = (const int*)d_in[6];
    const int* ctx  = (const int*)d_in[7];
    float* out = (float*)d_out;

    // split count from available workspace (deterministic: ws_size is fixed)
    const size_t per_split = (size_t)BB * H_KVN * (GQ * DD + GQ * 2) * sizeof(float);
    int nsplits = (int)(ws_size / per_split);
    if (nsplits > NSPLIT_MAX) nsplits = NSPLIT_MAX;
    if (nsplits < 1) nsplits = 1;

    float* ws_o  = (float*)d_ws;
    float* ws_ml = ws_o + (size_t)BB * H_KVN * nsplits * (GQ * DD);

    paged_decode_partial<<<BB * H_KVN * nsplits, 256, 0, stream>>>(
        q, k, v, kc, vc, bt, ctx, ws_o, ws_ml, nsplits);
    paged_decode_reduce<<<BB * H_KVN, 256, 0, stream>>>(ws_o, ws_ml, out, nsplits);
}

// Round 6
// 60.008 us; speedup vs baseline: 14.2786x; 1.1110x over previous
//
#include <hip/hip_runtime.h>
#include <math.h>

#define BB      32
#define H_KVN   8
#define GQ      4
#define H_QN    32
#define DD      128
#define PAGEN   16
#define PAGESN  128
#define NSPLITS 8

// (1/sqrt(128)) * log2(e): softmax in exp2 domain -> single v_exp_f32
#define SCALE2  (0.08838834764831845f * 1.4426950408889634f)
#define NEG_INF (-__builtin_huge_valf())

// Sum across each 16-lane DPP row via row_ror butterfly (8,4,2,1).
// VALU-only: no DS traffic, no lgkmcnt waits.
__device__ __forceinline__ float row_reduce_add(float v) {
    int x;
    x = __builtin_amdgcn_update_dpp(0, __float_as_int(v), 0x128, 0xf, 0xf, true); v += __int_as_float(x); // row_ror:8
    x = __builtin_amdgcn_update_dpp(0, __float_as_int(v), 0x124, 0xf, 0xf, true); v += __int_as_float(x); // row_ror:4
    x = __builtin_amdgcn_update_dpp(0, __float_as_int(v), 0x122, 0xf, 0xf, true); v += __int_as_float(x); // row_ror:2
    x = __builtin_amdgcn_update_dpp(0, __float_as_int(v), 0x121, 0xf, 0xf, true); v += __int_as_float(x); // row_ror:1
    return v;
}

__device__ __forceinline__ float dot8(const float4& a0, const float4& a1,
                                      const float4& b0, const float4& b1) {
    return a0.x*b0.x + a0.y*b0.y + a0.z*b0.z + a0.w*b0.w
         + a1.x*b1.x + a1.y*b1.y + a1.z*b1.z + a1.w*b1.w;
}

// Kernel 1: split-K partial attention. grid = B*H_KV*NSPLITS, block = 256 (4 waves).
// Each 16-lane row owns one position; lane l16 owns d = l16*8..+8. Main loop is
// BRANCH-FREE over full 32-position stripes (2 pos/row unroll, 8 dwordx4 in
// flight); a guarded 1-pos/row tail loop finishes the split. No device-scope
// fences (R4: per-block __threadfence = L2 flush = 10x regression).
__global__ __launch_bounds__(256)
void paged_decode_partial(const float* __restrict__ q,
                          const float* __restrict__ knew,
                          const float* __restrict__ vnew,
                          const float* __restrict__ kcache,
                          const float* __restrict__ vcache,
                          const int*   __restrict__ btab,
                          const int*   __restrict__ ctx_lens,
                          float*       __restrict__ ws_o,
                          float*       __restrict__ ws_ml)
{
    const int bid = blockIdx.x;
    const int s   = bid % NSPLITS;
    const int bh  = bid / NSPLITS;       // b*H_KV + h
    const int h   = bh % H_KVN;
    const int b   = bh / H_KVN;
    const int tid  = threadIdx.x;
    const int w    = tid >> 6;           // wave 0..3
    const int lane = tid & 63;
    const int g16  = lane >> 4;          // row (position sub-index) 0..3
    const int l16  = lane & 15;          // d-slice owner

    const int ctx   = ctx_lens[b];
    const int chunk = (((ctx + NSPLITS - 1) / NSPLITS) + 15) & ~15;  // page-aligned
    const int start = s * chunk;
    const int end   = min(start + chunk, ctx);
    const int cend  = min(end, ctx - 1);   // cache-resident portion of this split
    const int span  = cend - start;
    const int nfull = (span > 0) ? (span & ~31) : 0;   // full 32-pos stripes

    // q fragments: 4 grouped heads x 8 floats at d = l16*8
    float4 qa[GQ], qb[GQ];
    {
        const float* qp = q + ((size_t)b * H_QN + (size_t)h * GQ) * DD + l16 * 8;
        #pragma unroll
        for (int g = 0; g < GQ; ++g) {
            qa[g] = *(const float4*)(qp + g * DD);
            qb[g] = *(const float4*)(qp + g * DD + 4);
        }
    }

    float m[GQ], l[GQ], o[GQ][8];
    #pragma unroll
    for (int g = 0; g < GQ; ++g) {
        m[g] = NEG_INF; l[g] = 0.f;
        #pragma unroll
        for (int j = 0; j < 8; ++j) o[g][j] = 0.f;
    }

    const int* btb = btab + b * PAGESN;

    // Prologue: new token (position ctx-1) read from k/v (cache inputs are
    // never written). Done by wave 0 row 0 of the owning split while the
    // softmax state is empty: m=sc, l=1, o=v.
    if (w == 0 && g16 == 0 && start <= ctx - 1 && ctx - 1 < end) {
        const size_t off = ((size_t)b * H_KVN + h) * DD + l16 * 8;
        const float4 ka = *(const float4*)(knew + off);
        const float4 kb = *(const float4*)(knew + off + 4);
        const float4 va = *(const float4*)(vnew + off);
        const float4 vb = *(const float4*)(vnew + off + 4);
        const float ve[8] = { va.x, va.y, va.z, va.w, vb.x, vb.y, vb.z, vb.w };
        #pragma unroll
        for (int g = 0; g < GQ; ++g) {
            float d0 = row_reduce_add(dot8(qa[g], qb[g], ka, kb));
            m[g] = d0 * SCALE2;
            l[g] = 1.f;
            #pragma unroll
            for (int j = 0; j < 8; ++j) o[g][j] = ve[j];
        }
    }

    // Main loop: branch-free, 2 positions per row per iteration.
    // Stripe k covers positions [start+32k, start+32k+32); wave w owns
    // sub-range +w*8 .. +w*8+7 as rows {g16, g16+4}.
    for (int p0 = start + w * 8; p0 < start + nfull; p0 += 32) {
        const int pA = p0 + g16;
        const int pB = pA + 4;
        const int slotA = btb[pA >> 4] * PAGEN + (pA & (PAGEN - 1));
        const int slotB = btb[pB >> 4] * PAGEN + (pB & (PAGEN - 1));
        const size_t offA = ((size_t)slotA * H_KVN + h) * DD + l16 * 8;
        const size_t offB = ((size_t)slotB * H_KVN + h) * DD + l16 * 8;
        const float4 kA0 = *(const float4*)(kcache + offA);
        const float4 kA1 = *(const float4*)(kcache + offA + 4);
        const float4 vA0 = *(const float4*)(vcache + offA);
        const float4 vA1 = *(const float4*)(vcache + offA + 4);
        const float4 kB0 = *(const float4*)(kcache + offB);
        const float4 kB1 = *(const float4*)(kcache + offB + 4);
        const float4 vB0 = *(const float4*)(vcache + offB);
        const float4 vB1 = *(const float4*)(vcache + offB + 4);

        float dA[GQ], dB[GQ];
        #pragma unroll
        for (int g = 0; g < GQ; ++g) {
            dA[g] = dot8(qa[g], qb[g], kA0, kA1);
            dB[g] = dot8(qa[g], qb[g], kB0, kB1);
        }
        #pragma unroll
        for (int g = 0; g < GQ; ++g) {
            dA[g] = row_reduce_add(dA[g]);
            dB[g] = row_reduce_add(dB[g]);
        }
        const float vAe[8] = { vA0.x, vA0.y, vA0.z, vA0.w, vA1.x, vA1.y, vA1.z, vA1.w };
        const float vBe[8] = { vB0.x, vB0.y, vB0.z, vB0.w, vB1.x, vB1.y, vB1.z, vB1.w };
        #pragma unroll
        for (int g = 0; g < GQ; ++g) {
            const float scA  = dA[g] * SCALE2;
            const float scB  = dB[g] * SCALE2;
            const float nm   = fmaxf(m[g], fmaxf(scA, scB));
            const float corr = exp2f(m[g] - nm);   // m=-inf -> 0; nm finite here
            const float pa   = exp2f(scA - nm);
            const float pb   = exp2f(scB - nm);
            l[g] = l[g] * corr + pa + pb;
            m[g] = nm;
            #pragma unroll
            for (int j = 0; j < 8; ++j)
                o[g][j] = o[g][j] * corr + pa * vAe[j] + pb * vBe[j];
        }
    }

    // Tail: 1 position per row per iteration, guarded.
    for (int p = start + nfull + w * 4 + g16; p < cend; p += 16) {
        const int slot = btb[p >> 4] * PAGEN + (p & (PAGEN - 1));
        const size_t off = ((size_t)slot * H_KVN + h) * DD + l16 * 8;
        const float4 k0 = *(const float4*)(kcache + off);
        const float4 k1 = *(const float4*)(kcache + off + 4);
        const float4 v0 = *(const float4*)(vcache + off);
        const float4 v1 = *(const float4*)(vcache + off + 4);
        float d[GQ];
        #pragma unroll
        for (int g = 0; g < GQ; ++g) d[g] = dot8(qa[g], qb[g], k0, k1);
        #pragma unroll
        for (int g = 0; g < GQ; ++g) d[g] = row_reduce_add(d[g]);
        const float ve[8] = { v0.x, v0.y, v0.z, v0.w, v1.x, v1.y, v1.z, v1.w };
        #pragma unroll
        for (int g = 0; g < GQ; ++g) {
            const float sc   = d[g] * SCALE2;
            const float nm   = fmaxf(m[g], sc);
            const float corr = exp2f(m[g] - nm);
            const float pw   = exp2f(sc - nm);
            l[g] = l[g] * corr + pw;
            m[g] = nm;
            #pragma unroll
            for (int j = 0; j < 8; ++j)
                o[g][j] = o[g][j] * corr + pw * ve[j];
        }
    }

    // Merge the 4 rows of this wave (lane^16, lane^32); d-layout identical per row.
    #pragma unroll
    for (int msk = 16; msk <= 32; msk <<= 1) {
        #pragma unroll
        for (int g = 0; g < GQ; ++g) {
            const float mo = __shfl_xor(m[g], msk);
            const float lo = __shfl_xor(l[g], msk);
            const float M  = fmaxf(m[g], mo);
            const float c1 = (m[g] == NEG_INF) ? 0.f : exp2f(m[g] - M);
            const float c2 = (mo   == NEG_INF) ? 0.f : exp2f(mo   - M);
            l[g] = l[g] * c1 + lo * c2;
            #pragma unroll
            for (int j = 0; j < 8; ++j) {
                const float oo = __shfl_xor(o[g][j], msk);
                o[g][j] = o[g][j] * c1 + oo * c2;
            }
            m[g] = M;
        }
    }

    // Merge the 4 waves via LDS -> block partial -> workspace.
    __shared__ float o_lds[4][GQ][DD];       // 8 KB
    __shared__ float m_lds[4][GQ];
    __shared__ float l_lds[4][GQ];
    if (g16 == 0) {
        #pragma unroll
        for (int g = 0; g < GQ; ++g)
            #pragma unroll
            for (int j = 0; j < 8; ++j)
                o_lds[w][g][l16 * 8 + j] = o[g][j];
    }
    if (lane == 0) {
        #pragma unroll
        for (int g = 0; g < GQ; ++g) { m_lds[w][g] = m[g]; l_lds[w][g] = l[g]; }
    }
    __syncthreads();

    const size_t idx = (size_t)bh * NSPLITS + s;
    float* op  = ws_o  + idx * (GQ * DD);
    float* mlp = ws_ml + idx * (GQ * 2);

    for (int e = tid; e < GQ * DD; e += 256) {
        const int g = e >> 7;
        const int d = e & (DD - 1);
        const float M = fmaxf(fmaxf(m_lds[0][g], m_lds[1][g]),
                              fmaxf(m_lds[2][g], m_lds[3][g]));
        float acc = 0.f;
        #pragma unroll
        for (int ww = 0; ww < 4; ++ww) {
            const float mw  = m_lds[ww][g];
            const float wgt = (mw == NEG_INF) ? 0.f : exp2f(mw - M);
            acc += o_lds[ww][g][d] * wgt;
        }
        op[e] = acc;
    }
    if (tid < GQ) {
        const int g = tid;
        const float M = fmaxf(fmaxf(m_lds[0][g], m_lds[1][g]),
                              fmaxf(m_lds[2][g], m_lds[3][g]));
        float L = 0.f;
        #pragma unroll
        for (int ww = 0; ww < 4; ++ww) {
            const float mw  = m_lds[ww][g];
            const float wgt = (mw == NEG_INF) ? 0.f : exp2f(mw - M);
            L += l_lds[ww][g] * wgt;
        }
        mlp[g * 2]     = M;
        mlp[g * 2 + 1] = L;
    }
}

// Kernel 2: combine split partials and normalize. grid = B*H_KV, block = 256.
__global__ __launch_bounds__(256)
void paged_decode_reduce(const float* __restrict__ ws_o,
                         const float* __restrict__ ws_ml,
                         float*       __restrict__ out)
{
    const int bh  = blockIdx.x;            // b*H_KV + h
    const int tid = threadIdx.x;
    __shared__ float ML[GQ][2];

    const float* mlp = ws_ml + (size_t)bh * NSPLITS * (GQ * 2);
    if (tid < GQ) {
        const int g = tid;
        float M = NEG_INF;
        for (int s = 0; s < NSPLITS; ++s)
            M = fmaxf(M, mlp[s * GQ * 2 + g * 2]);
        float L = 0.f;
        for (int s = 0; s < NSPLITS; ++s) {
            const float mw  = mlp[s * GQ * 2 + g * 2];
            const float wgt = (mw == NEG_INF) ? 0.f : exp2f(mw - M);
            L += mlp[s * GQ * 2 + g * 2 + 1] * wgt;
        }
        ML[g][0] = M;
        ML[g][1] = L;   // ctx >= 1 guarantees L > 0
    }
    __syncthreads();

    const float* op = ws_o + (size_t)bh * NSPLITS * (GQ * DD);
    const int b = bh / H_KVN, h = bh % H_KVN;
    float* outp = out + ((size_t)b * H_QN + (size_t)h * GQ) * DD;

    for (int e = tid; e < GQ * DD; e += 256) {
        const int g = e >> 7;
        const float M = ML[g][0], L = ML[g][1];
        float acc = 0.f;
        for (int s = 0; s < NSPLITS; ++s) {
            const float mw  = mlp[s * GQ * 2 + g * 2];
            const float wgt = (mw == NEG_INF) ? 0.f : exp2f(mw - M);
            acc += op[s * GQ * DD + e] * wgt;
        }
        outp[e] = acc / L;
    }
}

extern "C" void kernel_launch(void* const* d_in, const int* in_sizes, int n_in,
                              void* d_out, int out_size, void* d_ws, size_t ws_size,
                              hipStream_t stream) {
    const float* q  = (const float*)d_in[0];
    const float* k  = (const float*)d_in[1];
    const float* v  = (const float*)d_in[2];
    const float* kc = (const float*)d_in[3];
    const float* vc = (const float*)d_in[4];
    // d_in[5] slot_mapping: unused — derived from block_tables + context_lens
    const int* bt   = (const int*)d_in[6];
    const int* ctx  = (const int*)d_in[7];
    float* out = (float*)d_out;

    float* ws_o  = (float*)d_ws;
    float* ws_ml = ws_o + (size_t)BB * H_KVN * NSPLITS * (GQ * DD);

    paged_decode_partial<<<BB * H_KVN * NSPLITS, 256, 0, stream>>>(
        q, k, v, kc, vc, bt, ctx, ws_o, ws_ml);
    paged_decode_reduce<<<BB * H_KVN, 256, 0, stream>>>(ws_o, ws_ml, out);
}

// Round 8
// 55.864 us; speedup vs baseline: 15.3378x; 1.0742x over previous
//
#include <hip/hip_runtime.h>
#include <math.h>

#define BB      32
#define H_KVN   8
#define GQ      4
#define H_QN    32
#define DD      128
#define PAGEN   16
#define PAGESN  128
#define NSPLITS 16

// (1/sqrt(128)) * log2(e): softmax in exp2 domain -> single v_exp_f32.
// Pre-multiplied into the q fragments at load time (saves 8 v_mul/iter).
#define SCALE2  (0.08838834764831845f * 1.4426950408889634f)
#define NEG_INF (-__builtin_huge_valf())

// Sum across each 16-lane DPP row via row_ror butterfly (8,4,2,1).
// VALU-only: no DS traffic, no lgkmcnt waits.
__device__ __forceinline__ float row_reduce_add(float v) {
    int x;
    x = __builtin_amdgcn_update_dpp(0, __float_as_int(v), 0x128, 0xf, 0xf, true); v += __int_as_float(x); // row_ror:8
    x = __builtin_amdgcn_update_dpp(0, __float_as_int(v), 0x124, 0xf, 0xf, true); v += __int_as_float(x); // row_ror:4
    x = __builtin_amdgcn_update_dpp(0, __float_as_int(v), 0x122, 0xf, 0xf, true); v += __int_as_float(x); // row_ror:2
    x = __builtin_amdgcn_update_dpp(0, __float_as_int(v), 0x121, 0xf, 0xf, true); v += __int_as_float(x); // row_ror:1
    return v;
}

__device__ __forceinline__ float dot8(const float4& a0, const float4& a1,
                                      const float4& b0, const float4& b1) {
    return a0.x*b0.x + a0.y*b0.y + a0.z*b0.z + a0.w*b0.w
         + a1.x*b1.x + a1.y*b1.y + a1.z*b1.z + a1.w*b1.w;
}

// Kernel 1: split-K partial attention. grid = B*H_KV*NSPLITS, block = 256 (4 waves).
// Each 16-lane row owns one position; lane l16 owns d = l16*8..+8. Main loop is
// branch-free over full 32-position stripes (2 pos/row unroll, 8 dwordx4 in
// flight); guarded 1-pos/row tail. No device-scope fences (R4 lesson: per-block
// __threadfence = L2 flush = 10x regression on CDNA4).
__global__ __launch_bounds__(256)
void paged_decode_partial(const float* __restrict__ q,
                          const float* __restrict__ knew,
                          const float* __restrict__ vnew,
                          const float* __restrict__ kcache,
                          const float* __restrict__ vcache,
                          const int*   __restrict__ btab,
                          const int*   __restrict__ ctx_lens,
                          float*       __restrict__ ws_o,
                          float*       __restrict__ ws_ml)
{
    const int bid = blockIdx.x;
    const int s   = bid % NSPLITS;
    const int bh  = bid / NSPLITS;       // b*H_KV + h
    const int h   = bh % H_KVN;
    const int b   = bh / H_KVN;
    const int tid  = threadIdx.x;
    const int w    = tid >> 6;           // wave 0..3
    const int lane = tid & 63;
    const int g16  = lane >> 4;          // row (position sub-index) 0..3
    const int l16  = lane & 15;          // d-slice owner

    const int ctx   = ctx_lens[b];
    const int chunk = (((ctx + NSPLITS - 1) / NSPLITS) + 15) & ~15;  // page-aligned
    const int start = s * chunk;
    const int end   = min(start + chunk, ctx);
    const int cend  = min(end, ctx - 1);   // cache-resident portion of this split
    const int span  = cend - start;
    const int nfull = (span > 0) ? (span & ~31) : 0;   // full 32-pos stripes

    // q fragments: 4 grouped heads x 8 floats at d = l16*8, PRE-SCALED by SCALE2
    float4 qa[GQ], qb[GQ];
    {
        const float* qp = q + ((size_t)b * H_QN + (size_t)h * GQ) * DD + l16 * 8;
        #pragma unroll
        for (int g = 0; g < GQ; ++g) {
            float4 a = *(const float4*)(qp + g * DD);
            float4 c = *(const float4*)(qp + g * DD + 4);
            a.x *= SCALE2; a.y *= SCALE2; a.z *= SCALE2; a.w *= SCALE2;
            c.x *= SCALE2; c.y *= SCALE2; c.z *= SCALE2; c.w *= SCALE2;
            qa[g] = a; qb[g] = c;
        }
    }

    float m[GQ], l[GQ], o[GQ][8];
    #pragma unroll
    for (int g = 0; g < GQ; ++g) {
        m[g] = NEG_INF; l[g] = 0.f;
        #pragma unroll
        for (int j = 0; j < 8; ++j) o[g][j] = 0.f;
    }

    const int* btb = btab + b * PAGESN;

    // Prologue: new token (position ctx-1) read from k/v (cache inputs never
    // written). Done by wave 0 row 0 of the owning split while the softmax
    // state is empty: m=sc, l=1, o=v. q is pre-scaled, so sc = reduced dot.
    if (w == 0 && g16 == 0 && start <= ctx - 1 && ctx - 1 < end) {
        const size_t off = ((size_t)b * H_KVN + h) * DD + l16 * 8;
        const float4 ka = *(const float4*)(knew + off);
        const float4 kb = *(const float4*)(knew + off + 4);
        const float4 va = *(const float4*)(vnew + off);
        const float4 vb = *(const float4*)(vnew + off + 4);
        const float ve[8] = { va.x, va.y, va.z, va.w, vb.x, vb.y, vb.z, vb.w };
        #pragma unroll
        for (int g = 0; g < GQ; ++g) {
            m[g] = row_reduce_add(dot8(qa[g], qb[g], ka, kb));
            l[g] = 1.f;
            #pragma unroll
            for (int j = 0; j < 8; ++j) o[g][j] = ve[j];
        }
    }

    // Main loop: branch-free, 2 positions per row per iteration.
    for (int p0 = start + w * 8; p0 < start + nfull; p0 += 32) {
        const int pA = p0 + g16;
        const int pB = pA + 4;
        const int slotA = btb[pA >> 4] * PAGEN + (pA & (PAGEN - 1));
        const int slotB = btb[pB >> 4] * PAGEN + (pB & (PAGEN - 1));
        const size_t offA = ((size_t)slotA * H_KVN + h) * DD + l16 * 8;
        const size_t offB = ((size_t)slotB * H_KVN + h) * DD + l16 * 8;
        const float4 kA0 = *(const float4*)(kcache + offA);
        const float4 kA1 = *(const float4*)(kcache + offA + 4);
        const float4 vA0 = *(const float4*)(vcache + offA);
        const float4 vA1 = *(const float4*)(vcache + offA + 4);
        const float4 kB0 = *(const float4*)(kcache + offB);
        const float4 kB1 = *(const float4*)(kcache + offB + 4);
        const float4 vB0 = *(const float4*)(vcache + offB);
        const float4 vB1 = *(const float4*)(vcache + offB + 4);

        float dA[GQ], dB[GQ];
        #pragma unroll
        for (int g = 0; g < GQ; ++g) {
            dA[g] = dot8(qa[g], qb[g], kA0, kA1);
            dB[g] = dot8(qa[g], qb[g], kB0, kB1);
        }
        #pragma unroll
        for (int g = 0; g < GQ; ++g) {
            dA[g] = row_reduce_add(dA[g]);
            dB[g] = row_reduce_add(dB[g]);
        }
        const float vAe[8] = { vA0.x, vA0.y, vA0.z, vA0.w, vA1.x, vA1.y, vA1.z, vA1.w };
        const float vBe[8] = { vB0.x, vB0.y, vB0.z, vB0.w, vB1.x, vB1.y, vB1.z, vB1.w };
        #pragma unroll
        for (int g = 0; g < GQ; ++g) {
            const float scA  = dA[g];               // already scaled via q
            const float scB  = dB[g];
            const float nm   = fmaxf(m[g], fmaxf(scA, scB));
            const float corr = exp2f(m[g] - nm);    // m=-inf -> 0; nm finite here
            const float pa   = exp2f(scA - nm);
            const float pb   = exp2f(scB - nm);
            l[g] = l[g] * corr + pa + pb;
            m[g] = nm;
            #pragma unroll
            for (int j = 0; j < 8; ++j)
                o[g][j] = o[g][j] * corr + pa * vAe[j] + pb * vBe[j];
        }
    }

    // Tail: 1 position per row per iteration, guarded.
    for (int p = start + nfull + w * 4 + g16; p < cend; p += 16) {
        const int slot = btb[p >> 4] * PAGEN + (p & (PAGEN - 1));
        const size_t off = ((size_t)slot * H_KVN + h) * DD + l16 * 8;
        const float4 k0 = *(const float4*)(kcache + off);
        const float4 k1 = *(const float4*)(kcache + off + 4);
        const float4 v0 = *(const float4*)(vcache + off);
        const float4 v1 = *(const float4*)(vcache + off + 4);
        float d[GQ];
        #pragma unroll
        for (int g = 0; g < GQ; ++g) d[g] = dot8(qa[g], qb[g], k0, k1);
        #pragma unroll
        for (int g = 0; g < GQ; ++g) d[g] = row_reduce_add(d[g]);
        const float ve[8] = { v0.x, v0.y, v0.z, v0.w, v1.x, v1.y, v1.z, v1.w };
        #pragma unroll
        for (int g = 0; g < GQ; ++g) {
            const float sc   = d[g];
            const float nm   = fmaxf(m[g], sc);
            const float corr = exp2f(m[g] - nm);
            const float pw   = exp2f(sc - nm);
            l[g] = l[g] * corr + pw;
            m[g] = nm;
            #pragma unroll
            for (int j = 0; j < 8; ++j)
                o[g][j] = o[g][j] * corr + pw * ve[j];
        }
    }

    // Merge the 4 rows of this wave (lane^16, lane^32); d-layout identical per row.
    #pragma unroll
    for (int msk = 16; msk <= 32; msk <<= 1) {
        #pragma unroll
        for (int g = 0; g < GQ; ++g) {
            const float mo = __shfl_xor(m[g], msk);
            const float lo = __shfl_xor(l[g], msk);
            const float M  = fmaxf(m[g], mo);
            const float c1 = (m[g] == NEG_INF) ? 0.f : exp2f(m[g] - M);
            const float c2 = (mo   == NEG_INF) ? 0.f : exp2f(mo   - M);
            l[g] = l[g] * c1 + lo * c2;
            #pragma unroll
            for (int j = 0; j < 8; ++j) {
                const float oo = __shfl_xor(o[g][j], msk);
                o[g][j] = o[g][j] * c1 + oo * c2;
            }
            m[g] = M;
        }
    }

    // Merge the 4 waves via LDS -> block partial -> workspace.
    __shared__ float o_lds[4][GQ][DD];       // 8 KB
    __shared__ float m_lds[4][GQ];
    __shared__ float l_lds[4][GQ];
    if (g16 == 0) {
        #pragma unroll
        for (int g = 0; g < GQ; ++g)
            #pragma unroll
            for (int j = 0; j < 8; ++j)
                o_lds[w][g][l16 * 8 + j] = o[g][j];
    }
    if (lane == 0) {
        #pragma unroll
        for (int g = 0; g < GQ; ++g) { m_lds[w][g] = m[g]; l_lds[w][g] = l[g]; }
    }
    __syncthreads();

    const size_t idx = (size_t)bh * NSPLITS + s;
    float* op  = ws_o  + idx * (GQ * DD);
    float* mlp = ws_ml + idx * (GQ * 2);

    for (int e = tid; e < GQ * DD; e += 256) {
        const int g = e >> 7;
        const int d = e & (DD - 1);
        const float M = fmaxf(fmaxf(m_lds[0][g], m_lds[1][g]),
                              fmaxf(m_lds[2][g], m_lds[3][g]));
        float acc = 0.f;
        #pragma unroll
        for (int ww = 0; ww < 4; ++ww) {
            const float mw  = m_lds[ww][g];
            const float wgt = (mw == NEG_INF) ? 0.f : exp2f(mw - M);
            acc += o_lds[ww][g][d] * wgt;
        }
        op[e] = acc;
    }
    if (tid < GQ) {
        const int g = tid;
        const float M = fmaxf(fmaxf(m_lds[0][g], m_lds[1][g]),
                              fmaxf(m_lds[2][g], m_lds[3][g]));
        float L = 0.f;
        #pragma unroll
        for (int ww = 0; ww < 4; ++ww) {
            const float mw  = m_lds[ww][g];
            const float wgt = (mw == NEG_INF) ? 0.f : exp2f(mw - M);
            L += l_lds[ww][g] * wgt;
        }
        mlp[g * 2]     = M;
        mlp[g * 2 + 1] = L;
    }
}

// Kernel 2: combine split partials and normalize. grid = B*H_KV, block = 256.
// Vectorized: 128 threads each own one float4 of the 512-elem output.
__global__ __launch_bounds__(256)
void paged_decode_reduce(const float* __restrict__ ws_o,
                         const float* __restrict__ ws_ml,
                         float*       __restrict__ out)
{
    const int bh  = blockIdx.x;            // b*H_KV + h
    const int tid = threadIdx.x;
    __shared__ float ML[GQ][2];

    const float* mlp = ws_ml + (size_t)bh * NSPLITS * (GQ * 2);
    if (tid < GQ) {
        const int g = tid;
        float M = NEG_INF;
        for (int s = 0; s < NSPLITS; ++s)
            M = fmaxf(M, mlp[s * GQ * 2 + g * 2]);
        float L = 0.f;
        for (int s = 0; s < NSPLITS; ++s) {
            const float mw  = mlp[s * GQ * 2 + g * 2];
            const float wgt = (mw == NEG_INF) ? 0.f : exp2f(mw - M);
            L += mlp[s * GQ * 2 + g * 2 + 1] * wgt;
        }
        ML[g][0] = M;
        ML[g][1] = L;   // ctx >= 1 guarantees L > 0
    }
    __syncthreads();

    if (tid >= (GQ * DD) / 4) return;      // 128 threads carry float4 each
    const int e4 = tid;                    // float4 index in [0,128)
    const int g  = (e4 * 4) >> 7;
    const float M = ML[g][0], L = ML[g][1];

    const float4* op4 = (const float4*)(ws_o + (size_t)bh * NSPLITS * (GQ * DD));
    float4 acc = make_float4(0.f, 0.f, 0.f, 0.f);
    for (int s = 0; s < NSPLITS; ++s) {
        const float mw  = mlp[s * GQ * 2 + g * 2];
        const float wgt = (mw == NEG_INF) ? 0.f : exp2f(mw - M);
        const float4 v  = op4[s * (GQ * DD / 4) + e4];
        acc.x += v.x * wgt; acc.y += v.y * wgt;
        acc.z += v.z * wgt; acc.w += v.w * wgt;
    }
    const float inv = 1.f / L;
    acc.x *= inv; acc.y *= inv; acc.z *= inv; acc.w *= inv;

    const int b = bh / H_KVN, h = bh % H_KVN;
    float4* outp = (float4*)(out + ((size_t)b * H_QN + (size_t)h * GQ) * DD);
    outp[e4] = acc;
}

extern "C" void kernel_launch(void* const* d_in, const int* in_sizes, int n_in,
                              void* d_out, int out_size, void* d_ws, size_t ws_size,
                              hipStream_t stream) {
    const float* q  = (const float*)d_in[0];
    const float* k  = (const float*)d_in[1];
    const float* v  = (const float*)d_in[2];
    const float* kc = (const float*)d_in[3];
    const float* vc = (const float*)d_in[4];
    // d_in[5] slot_mapping: unused — derived from block_tables + context_lens
    const int* bt   = (const int*)d_in[6];
    const int* ctx  = (const int*)d_in[7];
    float* out = (float*)d_out;

    float* ws_o  = (float*)d_ws;
    float* ws_ml = ws_o + (size_t)BB * H_KVN * NSPLITS * (GQ * DD);

    paged_decode_partial<<<BB * H_KVN * NSPLITS, 256, 0, stream>>>(
        q, k, v, kc, vc, bt, ctx, ws_o, ws_ml);
    paged_decode_reduce<<<BB * H_KVN, 256, 0, stream>>>(ws_o, ws_ml, out);
}